// Round 6
// baseline (568.417 us; speedup 1.0000x reference)
//
#include <hip/hip_runtime.h>

// Graph-attention sequential sweep as dataflow over the dependency DAG.
// Node i depends only on out-rows g[j] for j in neighbors[i], j<i, k<deg[i].
//
// R6 (on top of R5's confirmed counter-removal win, 659->260us):
//  (1) FUSE precomp into the dataflow kernel. Phase 0 (wait-free): each wave
//      computes ei/ej_orig for its own ids; ej_orig published with the same
//      nonzero-bits sentinel as ej_new. Phase 1 polls ej_orig for non-dep
//      neighbors (phase 0 never blocks -> bounded publish time -> no
//      deadlock cycle). Removes the separate kernel + ~165us fixed gap.
//  (2) 2048 blocks, __launch_bounds__(256,8): 32 waves/CU co-resident
//      (VGPR cap 64; R5 body measured 44). Doubles latency hiding and DAG
//      consumption width. Round-robin stride 8192 (consecutive ids on
//      distinct waves — R4 proved the opposite is catastrophic).
//
// Deadlock-freedom: all 8192 waves co-resident (8 blocks/CU x 256 CU, LDS=0,
// VGPR<=64). Phase 0 has no waits. In phase 1, the smallest unfinished id u
// is owned by wave u%8192; all ids < u are finished, so u's ej_new deps are
// published and its ej_orig deps publish in bounded time -> progress.
//
// Coherence scheme (NO buffer_inv / NO buffer_wbl2 anywhere):
//  - producer: out-row stores write-through to LLC (sc0 sc1); ej_new/ej_orig
//    via relaxed agent atomic stores; row payload ordered before ej_new by
//    an explicit s_waitcnt(0).
//  - consumer: polls ej_new/ej_orig with relaxed agent loads (sc1, no L2
//    inv); reads out-rows with NORMAL cached loads — safe because each 2KB
//    row occupies exclusive cachelines, is written once, and is first read
//    only after its ej_new is seen nonzero.

constexpr int NN = 50000;
constexpr int D  = 512;
constexpr int K  = 32;
constexpr int D4 = D / 4; // 128 float4 per row

typedef float v4f __attribute__((ext_vector_type(4)));

__device__ __forceinline__ void store_f4_llc(float* p, float4 v) {
    // write-through to the memory-side Infinity Cache (device coherence point)
    v4f vv; vv.x = v.x; vv.y = v.y; vv.z = v.z; vv.w = v.w;
    asm volatile("global_store_dwordx4 %0, %1, off sc0 sc1"
                 :: "v"(p), "v"(vv) : "memory");
}

__global__ __launch_bounds__(256, 8) void attn_dataflow(
    const float* __restrict__ feats,
    const int* __restrict__ neighbors, const int* __restrict__ deg,
    const float* __restrict__ wq_w, const float* __restrict__ wq_b,
    const float* __restrict__ wk_w, const float* __restrict__ wk_b,
    int* ej_new, int* ej_orig, float* ei_arr,
    float* out)
{
    const int lane   = threadIdx.x & 63;
    const int gwave  = (int)((blockIdx.x * blockDim.x + threadIdx.x) >> 6);
    const int nwaves = (int)((gridDim.x * blockDim.x) >> 6);
    const float4* f4  = (const float4*)feats;
    const float4* o4r = (const float4*)out;
    const float4* wq4 = (const float4*)wq_w;
    const float4* wk4 = (const float4*)wk_w;
    const float   wqb = wq_b[0];
    const float   wkb = wk_b[0];

    // ---------------- phase 0: wait-free precompute of ei / ej_orig ----------
    for (int id = gwave; id < NN; id += nwaves) {
        const float4* row = f4 + (size_t)id * D4;
        float4 v0 = row[lane],      v1 = row[lane + 64];
        float4 q0 = wq4[lane],      q1 = wq4[lane + 64];
        float4 k0 = wk4[lane],      k1 = wk4[lane + 64];
        float dq = v0.x*q0.x + v0.y*q0.y + v0.z*q0.z + v0.w*q0.w
                 + v1.x*q1.x + v1.y*q1.y + v1.z*q1.z + v1.w*q1.w;
        float dk = v0.x*k0.x + v0.y*k0.y + v0.z*k0.z + v0.w*k0.w
                 + v1.x*k1.x + v1.y*k1.y + v1.z*k1.z + v1.w*k1.w;
#pragma unroll
        for (int off = 32; off > 0; off >>= 1) {
            dq += __shfl_down(dq, off, 64);
            dk += __shfl_down(dk, off, 64);
        }
        if (lane == 0) {
            ei_arr[id] = dq + wqb;               // read only by this wave
            int b = __float_as_int(dk + wkb);
            if (b == 0) b = 1;                    // avoid not-ready sentinel
            __hip_atomic_store(&ej_orig[id], b,
                               __ATOMIC_RELAXED, __HIP_MEMORY_SCOPE_AGENT);
        }
    }

    // ---------------- phase 1: eager-softmax dataflow ------------------------
    for (int id = gwave; id < NN; id += nwaves) {
        const int d = deg[id];
        int nbr = 0;
        if (lane < K) nbr = neighbors[(size_t)id * K + lane];
        const bool valid = lane < d;                 // d <= 32
        const bool isdep = valid && (nbr < id);
        const int* watch = isdep ? ej_new : ej_orig; // per-lane poll target

        const float4 c0 = f4[(size_t)id * D4 + lane];
        const float4 c1 = f4[(size_t)id * D4 + lane + 64];
        const float eii = ei_arr[id];                // own wave wrote it

        float eij = 0.f;
        float4 acc0 = {0.f, 0.f, 0.f, 0.f};
        float4 acc1 = {0.f, 0.f, 0.f, 0.f};
        float m = -3.0e38f, s = 0.f;

        unsigned long long pend = 0;                 // ready, unprocessed
        unsigned long long wait = __ballot(valid);   // not yet seen ready

        while (pend | wait) {
            if (!pend) {
                // poll ALL remaining neighbors in parallel (one lane each)
                int pv = 0;
                const bool w = (wait >> lane) & 1ULL;
                if (w) pv = __hip_atomic_load(&watch[nbr], __ATOMIC_RELAXED,
                                              __HIP_MEMORY_SCOPE_AGENT);
                unsigned long long ready = __ballot(w && pv != 0);
                if (!ready) { __builtin_amdgcn_s_sleep(1); continue; }
                if (w && pv != 0) eij = eii * __int_as_float(pv);
                pend = ready;
                wait &= ~ready;
            }
            // take up to 4 ready neighbors (wave-uniform extraction)
            int cnt = 0;
            int   js[4]; float ee[4];
#pragma unroll
            for (int t = 0; t < 4; ++t) {
                if (pend) {
                    int k = (int)__ffsll(pend) - 1;
                    pend &= pend - 1;
                    ee[cnt] = __shfl(eij, k, 64);
                    js[cnt] = __shfl(nbr, k, 64);
                    ++cnt;
                }
            }
            // issue row loads FIRST so exp/rescale overlaps their flight
            float4 v0[4], v1[4];
#pragma unroll
            for (int t = 0; t < 4; ++t) {
                if (t < cnt) {
                    const float4* sp = (js[t] < id) ? (o4r + (size_t)js[t] * D4)
                                                    : (f4  + (size_t)js[t] * D4);
                    v0[t] = sp[lane];
                    v1[t] = sp[lane + 64];
                }
            }
            float mb = m;
#pragma unroll
            for (int t = 0; t < 4; ++t) if (t < cnt) mb = fmaxf(mb, ee[t]);
            if (mb > m) {
                const float r = __expf(m - mb);   // first time: exp(-inf)=0
                acc0.x *= r; acc0.y *= r; acc0.z *= r; acc0.w *= r;
                acc1.x *= r; acc1.y *= r; acc1.z *= r; acc1.w *= r;
                s *= r; m = mb;
            }
#pragma unroll
            for (int t = 0; t < 4; ++t) {
                if (t < cnt) {
                    const float wt = __expf(ee[t] - m);
                    s += wt;
                    acc0.x += wt * v0[t].x; acc0.y += wt * v0[t].y;
                    acc0.z += wt * v0[t].z; acc0.w += wt * v0[t].w;
                    acc1.x += wt * v1[t].x; acc1.y += wt * v1[t].y;
                    acc1.z += wt * v1[t].z; acc1.w += wt * v1[t].w;
                }
            }
        }

        const float inv_s = (s > 0.f) ? (1.0f / s) : 0.f;  // d==0 -> acc==0
        float4 g0 = {c0.x + acc0.x * inv_s, c0.y + acc0.y * inv_s,
                     c0.z + acc0.z * inv_s, c0.w + acc0.w * inv_s};
        float4 g1 = {c1.x + acc1.x * inv_s, c1.y + acc1.y * inv_s,
                     c1.z + acc1.z * inv_s, c1.w + acc1.w * inv_s};
        float* orow = out + (size_t)id * D;
        store_f4_llc(orow + 4 * lane,        g0);
        store_f4_llc(orow + 4 * (lane + 64), g1);

        // ej_new[id] = g . wk + bk  (computed while row stores are in flight)
        float4 w0 = wk4[lane], w1 = wk4[lane + 64];
        float pd = g0.x * w0.x + g0.y * w0.y + g0.z * w0.z + g0.w * w0.w
                 + g1.x * w1.x + g1.y * w1.y + g1.z * w1.z + g1.w * w1.w;
#pragma unroll
        for (int off = 32; off > 0; off >>= 1)
            pd += __shfl_xor(pd, off, 64);

        int bits = __float_as_int(pd + wkb);
        if (bits == 0) bits = 1;   // avoid the not-ready sentinel (+0.0 -> 1e-45)

        // order the row payload (at LLC) before the combined flag+payload
        __builtin_amdgcn_s_waitcnt(0);
        if (lane == 0)
            __hip_atomic_store(&ej_new[id], bits,
                               __ATOMIC_RELAXED, __HIP_MEMORY_SCOPE_AGENT);
    }
}

extern "C" void kernel_launch(void* const* d_in, const int* in_sizes, int n_in,
                              void* d_out, int out_size, void* d_ws, size_t ws_size,
                              hipStream_t stream)
{
    const float* feats     = (const float*)d_in[0];
    const float* wq_w      = (const float*)d_in[1];
    const float* wq_b      = (const float*)d_in[2];
    const float* wk_w      = (const float*)d_in[3];
    const float* wk_b      = (const float*)d_in[4];
    const int*   neighbors = (const int*)d_in[5];
    const int*   deg       = (const int*)d_in[6];
    float*       out       = (float*)d_out;

    // ws: [ej_new: NN i][pad 64][ej_orig: NN i][pad 64][ei: NN f]
    char*  ws      = (char*)d_ws;
    int*   ej_new  = (int*)ws;
    int*   ej_orig = ej_new + NN + 64;
    float* ei      = (float*)(ej_orig + NN + 64);

    // zero both sentinel arrays (ej_new + pad + ej_orig)
    (void)hipMemsetAsync(d_ws, 0, (size_t)(2 * NN + 128) * sizeof(int), stream);

    // 2048 blocks = 8192 waves, all co-resident (8 blocks/CU, launch_bounds(256,8))
    attn_dataflow<<<dim3(2048), dim3(256), 0, stream>>>(
        feats, neighbors, deg, wq_w, wq_b, wk_w, wk_b, ej_new, ej_orig, ei, out);
}

// Round 7
// 366.790 us; speedup vs baseline: 1.5497x; 1.5497x over previous
//
#include <hip/hip_runtime.h>
#include <hip/hip_fp16.h>

// Graph-attention sequential sweep as dataflow over the dependency DAG.
// Node i depends only on rows g[j] for j in neighbors[i], j<i, k<deg[i].
//
// R7 = R5 (verified 260us attn: static round-robin ids, 1024 blocks, separate
// precomp, eager online-softmax) + fp16 gather mirror:
//  - gathers read a f16 shadow pool (feats16 / out16, 1KB/row, 102 MB total
//    -> LLC-resident; halves gather bytes; one 16B load per row per lane).
//  - f32 out rows are no longer read by consumers -> plain cached stores.
//  - out16 is the flag-ordered write-through payload (sc0 sc1 + s_waitcnt
//    before the ej_new sentinel store).
//  - gather batch widened 4->8 rows (loads-in-flight stays 8; R4-verified
//    static dup-clamped extraction, dups get weight exp(-inf)=0).
//  - ws_size guard: if workspace < 102.4 MB mirror, fall back to verbatim
//    R5 f32 kernel (no failure mode).
//
// R6 lesson encoded: do NOT raise co-residency past 16 waves/CU (LLC thrash:
// +400MB HBM traffic, BW fell 3.7->3.1 TB/s); do NOT fuse precomp (phase
// barrier + polling regressed). Stride 4096: consecutive ids on distinct
// waves (R4: opposite is catastrophic).
//
// Deadlock-freedom: all 4096 waves co-resident (4 blocks/CU x 256 CU, LDS=0,
// VGPR<=128 via __launch_bounds__(256,4)). Smallest unfinished id u is owned
// by wave u%4096; all ids < u finished -> its deps are published -> progress.
//
// Coherence (NO buffer_inv / NO buffer_wbl2):
//  - producer: out16 row written through to LLC (sc0 sc1); ej_new (combined
//    payload+ready flag, bits==0 => not ready, +0.0 nudged to denormal) via
//    relaxed agent atomic store, ordered after out16 by s_waitcnt(0).
//  - consumer: polls ej_new with relaxed agent loads (sc1, no L2 inv);
//    reads out16 rows with NORMAL cached loads — safe because each 1KB row
//    occupies exclusive cachelines, is written once, and is first read only
//    after its ej_new is seen nonzero (no stale copy can exist in any cache).

constexpr int NN   = 50000;
constexpr int D    = 512;
constexpr int K    = 32;
constexpr int D4   = D / 4;   // 128 float4 per f32 row
constexpr int DU16 = D / 2;   // 256 u32 per f16 row (512 halves)

typedef float        v4f __attribute__((ext_vector_type(4)));
typedef unsigned int v4u __attribute__((ext_vector_type(4)));

__device__ __forceinline__ void store_f4_llc(float* p, float4 v) {
    v4f vv; vv.x = v.x; vv.y = v.y; vv.z = v.z; vv.w = v.w;
    asm volatile("global_store_dwordx4 %0, %1, off sc0 sc1"
                 :: "v"(p), "v"(vv) : "memory");
}
__device__ __forceinline__ void store_u4_llc(unsigned int* p, v4u v) {
    asm volatile("global_store_dwordx4 %0, %1, off sc0 sc1"
                 :: "v"(p), "v"(v) : "memory");
}
__device__ __forceinline__ unsigned int packh2(float a, float b) {
    __half2 h = __floats2half2_rn(a, b);
    return *reinterpret_cast<unsigned int*>(&h);
}
__device__ __forceinline__ float2 unpackh2(unsigned int u) {
    __half2 h = *reinterpret_cast<__half2*>(&u);
    return __half22float2(h);
}

__global__ __launch_bounds__(256) void precomp_kernel(
    const float* __restrict__ feats,
    const float* __restrict__ wq_w, const float* __restrict__ wq_b,
    const float* __restrict__ wk_w, const float* __restrict__ wk_b,
    float* __restrict__ ei, float* __restrict__ ej_orig,
    unsigned int* __restrict__ feats16)   // may be null (f32 fallback path)
{
    int gw   = (int)((blockIdx.x * blockDim.x + threadIdx.x) >> 6); // global wave id
    int lane = threadIdx.x & 63;
    if (gw >= NN) return;
    const float4* row = (const float4*)feats + (size_t)gw * D4;
    const float4* q4  = (const float4*)wq_w;
    const float4* k4  = (const float4*)wk_w;
    // lane owns elements [8*lane .. 8*lane+7]
    float4 v0 = row[2 * lane], v1 = row[2 * lane + 1];
    float4 q0 = q4[2 * lane],  q1 = q4[2 * lane + 1];
    float4 k0 = k4[2 * lane],  k1 = k4[2 * lane + 1];
    float dq = v0.x*q0.x + v0.y*q0.y + v0.z*q0.z + v0.w*q0.w
             + v1.x*q1.x + v1.y*q1.y + v1.z*q1.z + v1.w*q1.w;
    float dk = v0.x*k0.x + v0.y*k0.y + v0.z*k0.z + v0.w*k0.w
             + v1.x*k1.x + v1.y*k1.y + v1.z*k1.z + v1.w*k1.w;
#pragma unroll
    for (int off = 32; off > 0; off >>= 1) {
        dq += __shfl_down(dq, off, 64);
        dk += __shfl_down(dk, off, 64);
    }
    if (feats16) {
        v4u p;
        p.x = packh2(v0.x, v0.y); p.y = packh2(v0.z, v0.w);
        p.z = packh2(v1.x, v1.y); p.w = packh2(v1.z, v1.w);
        *(v4u*)(feats16 + (size_t)gw * DU16 + 4 * lane) = p;  // plain store;
        // visible to the attn kernel via stream-order kernel boundary.
    }
    if (lane == 0) {
        ei[gw]      = dq + wq_b[0];
        ej_orig[gw] = dk + wk_b[0];
    }
}

// ---------------- fp16-gather dataflow kernel (primary path) ----------------
__global__ __launch_bounds__(256, 4) void attn_dataflow_h16(
    const float* __restrict__ feats,
    const int* __restrict__ neighbors, const int* __restrict__ deg,
    const float* __restrict__ ei_arr, const float* __restrict__ ej_orig,
    const float* __restrict__ wk_w, const float* __restrict__ wk_b,
    const unsigned int* __restrict__ feats16, unsigned int* __restrict__ out16,
    int* ej_new, float* out)
{
    const int lane   = threadIdx.x & 63;
    const int gwave  = (int)((blockIdx.x * blockDim.x + threadIdx.x) >> 6);
    const int nwaves = (int)((gridDim.x * blockDim.x) >> 6);
    const float4* f4  = (const float4*)feats;
    const float4* wk4 = (const float4*)wk_w;
    const float   wkb = wk_b[0];

    for (int id = gwave; id < NN; id += nwaves) {
        const int d = deg[id];
        int nbr = 0;
        if (lane < K) nbr = neighbors[(size_t)id * K + lane];
        const bool valid = lane < d;                 // d <= 32
        const bool isdep = valid && (nbr < id);

        // center row, lane elements [8*lane .. 8*lane+7] (f32, full precision)
        const float4 c0 = f4[(size_t)id * D4 + 2 * lane];
        const float4 c1 = f4[(size_t)id * D4 + 2 * lane + 1];
        const float eii = ei_arr[id];

        float eij = 0.f;
        if (valid && !isdep) eij = eii * ej_orig[nbr];

        // ---- eager online-softmax over ready neighbors ----
        float4 acc0 = {0.f, 0.f, 0.f, 0.f};
        float4 acc1 = {0.f, 0.f, 0.f, 0.f};
        float m = -3.0e38f, s = 0.f;

        unsigned long long pend = __ballot(valid && !isdep);
        unsigned long long wait = __ballot(isdep);

        while (pend | wait) {
            if (!pend) {
                // poll ALL remaining deps in parallel (one lane each)
                int pv = 0;
                const bool w = (wait >> lane) & 1ULL;
                if (w) pv = __hip_atomic_load(&ej_new[nbr], __ATOMIC_RELAXED,
                                              __HIP_MEMORY_SCOPE_AGENT);
                unsigned long long ready = __ballot(w && pv != 0);
                if (!ready) { __builtin_amdgcn_s_sleep(1); continue; }
                if (w && pv != 0) eij = eii * __int_as_float(pv);
                pend = ready;
                wait &= ~ready;
            }
            // take up to 8 ready neighbors; static indexing, duplicates
            // clamp to the last valid slot and get weight exp(-inf) = 0.
            int js_[8]; float ee[8]; int klast = 0;
#pragma unroll
            for (int t = 0; t < 8; ++t) {
                const bool has = (pend != 0);            // wave-uniform
                int k = has ? ((int)__ffsll(pend) - 1) : klast;
                if (has) pend &= pend - 1;
                klast = k;
                float ev = __shfl(eij, k, 64);
                ee[t] = has ? ev : -3.0e38f;
                js_[t] = __shfl(nbr, k, 64);
            }
            // issue all 8 f16-row loads (16B/lane each) before any exp/rescale
            v4u pv8[8];
#pragma unroll
            for (int t = 0; t < 8; ++t) {
                const unsigned int* sp = ((js_[t] < id) ? out16 : feats16)
                                         + (size_t)js_[t] * DU16 + 4 * lane;
                pv8[t] = *(const v4u*)sp;
            }
            float mb = m;
#pragma unroll
            for (int t = 0; t < 8; ++t) mb = fmaxf(mb, ee[t]);
            if (mb > m) {
                const float r = __expf(m - mb);   // first time: exp(-inf)=0
                acc0.x *= r; acc0.y *= r; acc0.z *= r; acc0.w *= r;
                acc1.x *= r; acc1.y *= r; acc1.z *= r; acc1.w *= r;
                s *= r; m = mb;
            }
#pragma unroll
            for (int t = 0; t < 8; ++t) {
                const float wt = __expf(ee[t] - m);      // dup: exp(-inf)=0
                s += wt;
                float2 f0 = unpackh2(pv8[t].x), f1 = unpackh2(pv8[t].y);
                float2 f2 = unpackh2(pv8[t].z), f3 = unpackh2(pv8[t].w);
                acc0.x += wt * f0.x; acc0.y += wt * f0.y;
                acc0.z += wt * f1.x; acc0.w += wt * f1.y;
                acc1.x += wt * f2.x; acc1.y += wt * f2.y;
                acc1.z += wt * f3.x; acc1.w += wt * f3.y;
            }
        }

        const float inv_s = (s > 0.f) ? (1.0f / s) : 0.f;  // d==0 -> acc==0
        float4 g0 = {c0.x + acc0.x * inv_s, c0.y + acc0.y * inv_s,
                     c0.z + acc0.z * inv_s, c0.w + acc0.w * inv_s};
        float4 g1 = {c1.x + acc1.x * inv_s, c1.y + acc1.y * inv_s,
                     c1.z + acc1.z * inv_s, c1.w + acc1.w * inv_s};

        // f32 result row: nobody reads it on-device -> plain cached stores
        float4* orow4 = (float4*)out + (size_t)id * D4;
        orow4[2 * lane]     = g0;
        orow4[2 * lane + 1] = g1;

        // f16 mirror row: the gather payload, write-through + flag-ordered
        v4u pg;
        pg.x = packh2(g0.x, g0.y); pg.y = packh2(g0.z, g0.w);
        pg.z = packh2(g1.x, g1.y); pg.w = packh2(g1.z, g1.w);
        store_u4_llc(out16 + (size_t)id * DU16 + 4 * lane, pg);

        // ej_new[id] = g . wk + bk  (computed while stores are in flight)
        float4 w0 = wk4[2 * lane], w1 = wk4[2 * lane + 1];
        float pd = g0.x * w0.x + g0.y * w0.y + g0.z * w0.z + g0.w * w0.w
                 + g1.x * w1.x + g1.y * w1.y + g1.z * w1.z + g1.w * w1.w;
#pragma unroll
        for (int off = 32; off > 0; off >>= 1)
            pd += __shfl_xor(pd, off, 64);

        int bits = __float_as_int(pd + wkb);
        if (bits == 0) bits = 1;   // avoid the not-ready sentinel

        // order the out16 payload (at LLC) before the combined flag+payload
        __builtin_amdgcn_s_waitcnt(0);
        if (lane == 0)
            __hip_atomic_store(&ej_new[id], bits,
                               __ATOMIC_RELAXED, __HIP_MEMORY_SCOPE_AGENT);
    }
}

// ---------------- f32 fallback (verbatim R5 kernel, 260us verified) ---------
__global__ __launch_bounds__(256, 4) void attn_dataflow_f32(
    const float* __restrict__ feats,
    const int* __restrict__ neighbors, const int* __restrict__ deg,
    const float* __restrict__ ei_arr, const float* __restrict__ ej_orig,
    const float* __restrict__ wk_w, const float* __restrict__ wk_b,
    int* ej_new, float* out)
{
    const int lane   = threadIdx.x & 63;
    const int gwave  = (int)((blockIdx.x * blockDim.x + threadIdx.x) >> 6);
    const int nwaves = (int)((gridDim.x * blockDim.x) >> 6);
    const float4* f4  = (const float4*)feats;
    const float4* o4r = (const float4*)out;
    const float4* wk4 = (const float4*)wk_w;
    const float   wkb = wk_b[0];

    for (int id = gwave; id < NN; id += nwaves) {
        const int d = deg[id];
        int nbr = 0;
        if (lane < K) nbr = neighbors[(size_t)id * K + lane];
        const bool valid = lane < d;
        const bool isdep = valid && (nbr < id);

        const float4 c0 = f4[(size_t)id * D4 + lane];
        const float4 c1 = f4[(size_t)id * D4 + lane + 64];
        const float eii = ei_arr[id];

        float eij = 0.f;
        if (valid && !isdep) eij = eii * ej_orig[nbr];

        float4 acc0 = {0.f, 0.f, 0.f, 0.f};
        float4 acc1 = {0.f, 0.f, 0.f, 0.f};
        float m = -3.0e38f, s = 0.f;

        unsigned long long pend = __ballot(valid && !isdep);
        unsigned long long wait = __ballot(isdep);

        while (pend | wait) {
            if (!pend) {
                int pv = 0;
                const bool w = (wait >> lane) & 1ULL;
                if (w) pv = __hip_atomic_load(&ej_new[nbr], __ATOMIC_RELAXED,
                                              __HIP_MEMORY_SCOPE_AGENT);
                unsigned long long ready = __ballot(w && pv != 0);
                if (!ready) { __builtin_amdgcn_s_sleep(1); continue; }
                if (w && pv != 0) eij = eii * __int_as_float(pv);
                pend = ready;
                wait &= ~ready;
            }
            int cnt = 0;
            int   js[4]; float ee[4];
#pragma unroll
            for (int t = 0; t < 4; ++t) {
                if (pend) {
                    int k = (int)__ffsll(pend) - 1;
                    pend &= pend - 1;
                    ee[cnt] = __shfl(eij, k, 64);
                    js[cnt] = __shfl(nbr, k, 64);
                    ++cnt;
                }
            }
            float4 v0[4], v1[4];
#pragma unroll
            for (int t = 0; t < 4; ++t) {
                if (t < cnt) {
                    const float4* sp = (js[t] < id) ? (o4r + (size_t)js[t] * D4)
                                                    : (f4  + (size_t)js[t] * D4);
                    v0[t] = sp[lane];
                    v1[t] = sp[lane + 64];
                }
            }
            float mb = m;
#pragma unroll
            for (int t = 0; t < 4; ++t) if (t < cnt) mb = fmaxf(mb, ee[t]);
            if (mb > m) {
                const float r = __expf(m - mb);
                acc0.x *= r; acc0.y *= r; acc0.z *= r; acc0.w *= r;
                acc1.x *= r; acc1.y *= r; acc1.z *= r; acc1.w *= r;
                s *= r; m = mb;
            }
#pragma unroll
            for (int t = 0; t < 4; ++t) {
                if (t < cnt) {
                    const float wt = __expf(ee[t] - m);
                    s += wt;
                    acc0.x += wt * v0[t].x; acc0.y += wt * v0[t].y;
                    acc0.z += wt * v0[t].z; acc0.w += wt * v0[t].w;
                    acc1.x += wt * v1[t].x; acc1.y += wt * v1[t].y;
                    acc1.z += wt * v1[t].z; acc1.w += wt * v1[t].w;
                }
            }
        }

        const float inv_s = (s > 0.f) ? (1.0f / s) : 0.f;
        float4 g0 = {c0.x + acc0.x * inv_s, c0.y + acc0.y * inv_s,
                     c0.z + acc0.z * inv_s, c0.w + acc0.w * inv_s};
        float4 g1 = {c1.x + acc1.x * inv_s, c1.y + acc1.y * inv_s,
                     c1.z + acc1.z * inv_s, c1.w + acc1.w * inv_s};
        float* orow = out + (size_t)id * D;
        store_f4_llc(orow + 4 * lane,        g0);
        store_f4_llc(orow + 4 * (lane + 64), g1);

        float4 w0 = wk4[lane], w1 = wk4[lane + 64];
        float pd = g0.x * w0.x + g0.y * w0.y + g0.z * w0.z + g0.w * w0.w
                 + g1.x * w1.x + g1.y * w1.y + g1.z * w1.z + g1.w * w1.w;
#pragma unroll
        for (int off = 32; off > 0; off >>= 1)
            pd += __shfl_xor(pd, off, 64);

        int bits = __float_as_int(pd + wkb);
        if (bits == 0) bits = 1;

        __builtin_amdgcn_s_waitcnt(0);
        if (lane == 0)
            __hip_atomic_store(&ej_new[id], bits,
                               __ATOMIC_RELAXED, __HIP_MEMORY_SCOPE_AGENT);
    }
}

extern "C" void kernel_launch(void* const* d_in, const int* in_sizes, int n_in,
                              void* d_out, int out_size, void* d_ws, size_t ws_size,
                              hipStream_t stream)
{
    const float* feats     = (const float*)d_in[0];
    const float* wq_w      = (const float*)d_in[1];
    const float* wq_b      = (const float*)d_in[2];
    const float* wk_w      = (const float*)d_in[3];
    const float* wk_b      = (const float*)d_in[4];
    const int*   neighbors = (const int*)d_in[5];
    const int*   deg       = (const int*)d_in[6];
    float*       out       = (float*)d_out;

    // ws: [ej_new: NN i][pad 64][ei: NN f][ej_orig: NN f] | align1024 |
    //     [feats16: NN*1KB][out16: NN*1KB]   (f16 mirror, if ws_size allows)
    char*  ws      = (char*)d_ws;
    int*   ej_new  = (int*)ws;
    float* ei      = (float*)(ej_new + NN + 64);
    float* ej_orig = ei + NN;
    size_t scal_end = (size_t)((char*)(ej_orig + NN) - ws);
    size_t f16_off  = (scal_end + 1023) & ~(size_t)1023;
    size_t f16_need = 2ull * NN * DU16 * sizeof(unsigned int);  // 102.4 MB
    const bool use16 = (ws_size >= f16_off + f16_need);
    unsigned int* feats16 = (unsigned int*)(ws + f16_off);
    unsigned int* out16   = feats16 + (size_t)NN * DU16;

    (void)hipMemsetAsync(d_ws, 0, (size_t)NN * sizeof(int), stream);  // ej_new=0

    dim3 pb(256), pg((NN + 3) / 4);
    precomp_kernel<<<pg, pb, 0, stream>>>(feats, wq_w, wq_b, wk_w, wk_b,
                                          ei, ej_orig, use16 ? feats16 : nullptr);

    if (use16) {
        attn_dataflow_h16<<<dim3(1024), dim3(256), 0, stream>>>(
            feats, neighbors, deg, ei, ej_orig, wk_w, wk_b,
            feats16, out16, ej_new, out);
    } else {
        attn_dataflow_f32<<<dim3(1024), dim3(256), 0, stream>>>(
            feats, neighbors, deg, ei, ej_orig, wk_w, wk_b, ej_new, out);
    }
}